// Round 2
// baseline (1013.047 us; speedup 1.0000x reference)
//
#include <hip/hip_runtime.h>
#include <stdint.h>
#include <stddef.h>

// MaskedLinear: y = x @ W.T + b, rows zeroed where amask==0.
// N=1e6, IN=OUT=128, fp32 in/out. bf16 MFMA compute (2% absmax budget).
//
// R4: recover R3's regression + improve the epilogue.
//  - R3 post-mortem: nontemporal stores broke L2 write-merging of the 64B
//    half-line store segments -> partial-line writebacks -> RMW traffic
//    (FETCH 954 MB vs ~260 expected, WRITE 614 vs 512, hbm_bytes 1.6 GB,
//    422us). Reverted to plain stores.
//  - Operand swap: compute mfma(W_frag, x_frag) = out^T per tile. With the
//    verified C/D layout (col=lane&15, row=(lane>>4)*4+reg), each lane now
//    holds 4 CONSECUTIVE out columns of its own x row -> epilogue is 8
//    aligned float4 stores per lane (vs 32 strided scalar dwords). Input
//    fragments are unchanged: A and B frags share the same lane mapping
//    (m/n = lane&15, k = (lane>>4)*8+j), so the staged W fragment and the
//    x row-contiguous load both work as-is.
//  - Mask: x frags zeroed per-lane when masked AND bias-init zeroed per-lane
//    -> masked rows produce exact 0.0f with unconditional stores.
//  - Kept from R3 (verified fine): W as bf16 B-fragments in 32 KiB LDS
//    (conflict-free ds_read_b128, SQ_LDS_BANK_CONFLICT=0), VGPR 64,
//    __launch_bounds__(256,4), 4 blocks/CU, 1024 blocks.

typedef __attribute__((ext_vector_type(8))) short short8;   // 8 bf16 = 4 VGPRs
typedef __attribute__((ext_vector_type(4))) float f32x4;    // MFMA acc / vec4

__device__ __forceinline__ unsigned short f2bf(float f) {
    union { float f; unsigned int u; } v; v.f = f;
    unsigned int u = v.u;
    // round-to-nearest-even
    unsigned int r = (u + 0x7FFFu + ((u >> 16) & 1u)) >> 16;
    return (unsigned short)r;
}

__device__ __forceinline__ short8 pack8(f32x4 lo, f32x4 hi) {
    short8 r;
    r[0] = (short)f2bf(lo[0]); r[1] = (short)f2bf(lo[1]);
    r[2] = (short)f2bf(lo[2]); r[3] = (short)f2bf(lo[3]);
    r[4] = (short)f2bf(hi[0]); r[5] = (short)f2bf(hi[1]);
    r[6] = (short)f2bf(hi[2]); r[7] = (short)f2bf(hi[3]);
    return r;
}

__global__ __launch_bounds__(256, 4)
void masked_linear_kernel(const float* __restrict__ x,
                          const int* __restrict__ amask,
                          const float* __restrict__ W,
                          const float* __restrict__ bias,
                          float* __restrict__ out,
                          int n_tiles, int n_waves)
{
    // 32 fragments (t=0..7 col-tiles x s=0..3 k-tiles) x 64 lanes x 16 B
    __shared__ short8 wlds[2048];   // 32 KiB

    const int tid  = threadIdx.x;
    const int lane = tid & 63;
    const int wid  = blockIdx.x * (blockDim.x >> 6) + (tid >> 6);
    const int ln   = lane & 15;   // lane's x-row offset within tile / frag m-n idx
    const int kg   = lane >> 4;   // k-group (0..3)

    // ---- stage W -> LDS as bf16 fragments ----
    // entry e = f*64 + l, f = t*4+s. Content for reading-lane l:
    //   frag[i][k] = W[t*16 + (l&15)][s*32 + (l>>4)*8 + j]
    for (int e = tid; e < 2048; e += 256) {
        const int f = e >> 6, l = e & 63;
        const int t = f >> 2, s = f & 3;
        const int n  = t * 16 + (l & 15);
        const int k0 = s * 32 + (l >> 4) * 8;
        const f32x4* p = reinterpret_cast<const f32x4*>(W + n * 128 + k0);
        wlds[e] = pack8(p[0], p[1]);
    }
    // bias for this lane's 4 consecutive out-cols per t-tile:
    // acc[t][r] = out[.][t*16 + kg*4 + r]
    f32x4 bv4[8];
#pragma unroll
    for (int t = 0; t < 8; ++t)
        bv4[t] = *reinterpret_cast<const f32x4*>(bias + t * 16 + (kg << 2));
    __syncthreads();

    const f32x4 zero4 = {0.f, 0.f, 0.f, 0.f};

    for (int tile = wid; tile < n_tiles; tile += n_waves) {
        const int r0   = tile << 4;
        const int arow = r0 + ln;                 // this lane's x/out row
        const bool m   = amask[arow] != 0;        // 4-byte word test

        // ---- x fragments: predicated direct-from-global loads (B operand)
        const float* xr = x + (size_t)arow * 128 + kg * 8;
        short8 a[4];
#pragma unroll
        for (int s = 0; s < 4; ++s) {
            f32x4 lo = zero4, hi = zero4;
            if (m) {
                const f32x4* p = reinterpret_cast<const f32x4*>(xr + s * 32);
                lo = p[0]; hi = p[1];
            }
            a[s] = pack8(lo, hi);
        }

        // ---- acc init: bias (zeroed for masked-out rows; a==0 keeps it 0)
        f32x4 acc[8];
#pragma unroll
        for (int t = 0; t < 8; ++t)
            acc[t] = m ? bv4[t] : zero4;

        // ---- MFMA, swapped operands: D = Wtile * x^T -> out[row][4 cols]/lane
#pragma unroll
        for (int s = 0; s < 4; ++s)
#pragma unroll
            for (int t = 0; t < 8; ++t)
                acc[t] = __builtin_amdgcn_mfma_f32_16x16x32_bf16(
                             wlds[(t * 4 + s) * 64 + lane], a[s], acc[t], 0, 0, 0);

        // ---- store: lane ln owns row r0+ln, cols t*16 + kg*4 + {0..3}
        float* orow = out + (size_t)arow * 128 + (kg << 2);
#pragma unroll
        for (int t = 0; t < 8; ++t)
            *reinterpret_cast<f32x4*>(orow + t * 16) = acc[t];
    }
}

extern "C" void kernel_launch(void* const* d_in, const int* in_sizes, int n_in,
                              void* d_out, int out_size, void* d_ws, size_t ws_size,
                              hipStream_t stream) {
    const float* x     = (const float*)d_in[0];
    const int*   amask = (const int*)d_in[1];
    const float* W     = (const float*)d_in[2];
    const float* b     = (const float*)d_in[3];
    float*       out   = (float*)d_out;

    const int n_rows  = in_sizes[1];      // 1,000,000 (multiple of 16)
    const int n_tiles = n_rows >> 4;      // 62,500
    // 4 blocks/CU resident (VGPR<=128, LDS 32KB): 256 CU * 4 = 1024 blocks.
    const int blocks  = 1024;
    const int n_waves = blocks * 4;

    hipLaunchKernelGGL(masked_linear_kernel, dim3(blocks), dim3(256), 0, stream,
                       x, amask, W, b, out, n_tiles, n_waves);
}

// Round 3
// 788.366 us; speedup vs baseline: 1.2850x; 1.2850x over previous
//
#include <hip/hip_runtime.h>
#include <stdint.h>
#include <stddef.h>

// MaskedLinear: y = x @ W.T + b, rows zeroed where amask==0.
// N=1e6, IN=OUT=128, fp32 in/out. bf16 MFMA compute (2% absmax budget).
//
// R5: kill the out write-allocate fetch.
//  - R4 post-mortem: FETCH 969 MB / WRITE 611 MB identical to R3 despite a
//    completely different store path -> nt-store theory WRONG. The excess is
//    write-allocate: every out 128B line is first touched by a partial-line
//    store segment (16 scattered 64B pieces per instruction), so L2 fetches
//    the line from HBM before overwriting it (~512 MB), plus half-dirty
//    evict/refetch (+99 MB WRITE). Harness fill kernel proves full-line
//    contiguous stores elide this (2.048 GB written, 14.5 KB fetched).
//  - Fix: per-wave LDS bounce of the 16x128 out tile in 2 passes of 4 KB
//    ([16][68] f32, +16B row pad -> conflict-free), intra-wave (no barrier),
//    then 1KB-contiguous dwordx4 stores: each 128B line fully covered by a
//    single instruction -> no allocate-fetch.
//  - LDS 32K (W frags) + 17K (4 waves x [16][68] f32) = 49K -> 3 blocks/CU.
//  - Kept verified-good: W bf16 fragments in LDS (0 bank conflicts), swapped
//    mfma(W,x) so lane holds 4 consecutive out cols of its own row,
//    exec-predicated x loads (masked rows never fetched), bias/zero acc init.
//
// Layout facts (verified m89): A/B frag lane mapping m/n=lane&15,
// k=(lane>>4)*8+j; C/D col=lane&15, row=(lane>>4)*4+reg.
// amask is 4-byte words; test word != 0.

typedef __attribute__((ext_vector_type(8))) short short8;   // 8 bf16 = 4 VGPRs
typedef __attribute__((ext_vector_type(4))) float f32x4;    // MFMA acc / vec4

__device__ __forceinline__ unsigned short f2bf(float f) {
    union { float f; unsigned int u; } v; v.f = f;
    unsigned int u = v.u;
    // round-to-nearest-even
    unsigned int r = (u + 0x7FFFu + ((u >> 16) & 1u)) >> 16;
    return (unsigned short)r;
}

__device__ __forceinline__ short8 pack8(f32x4 lo, f32x4 hi) {
    short8 r;
    r[0] = (short)f2bf(lo[0]); r[1] = (short)f2bf(lo[1]);
    r[2] = (short)f2bf(lo[2]); r[3] = (short)f2bf(lo[3]);
    r[4] = (short)f2bf(hi[0]); r[5] = (short)f2bf(hi[1]);
    r[6] = (short)f2bf(hi[2]); r[7] = (short)f2bf(hi[3]);
    return r;
}

__global__ __launch_bounds__(256, 4)
void masked_linear_kernel(const float* __restrict__ x,
                          const int* __restrict__ amask,
                          const float* __restrict__ W,
                          const float* __restrict__ bias,
                          float* __restrict__ out,
                          int n_tiles, int n_waves)
{
    // 32 W-fragments (t=0..7 col-tiles x s=0..3 k-tiles) x 64 lanes x 16 B
    __shared__ short8 wlds[2048];            // 32 KiB
    // per-wave out-tile bounce: 16 rows x 64 cols (+4 pad) f32, 2 passes
    __shared__ float obnc[4][16][68];        // 17 KiB

    const int tid  = threadIdx.x;
    const int lane = tid & 63;
    const int wib  = tid >> 6;               // wave index in block (0..3)
    const int wid  = blockIdx.x * (blockDim.x >> 6) + wib;
    const int ln   = lane & 15;   // lane's row offset in tile / frag m-n idx
    const int kg   = lane >> 4;   // k-group (0..3)

    // ---- stage W -> LDS as bf16 fragments ----
    // entry e = f*64 + l, f = t*4+s. Content for reading-lane l:
    //   frag[i][k] = W[t*16 + (l&15)][s*32 + (l>>4)*8 + j]
    for (int e = tid; e < 2048; e += 256) {
        const int f = e >> 6, l = e & 63;
        const int t = f >> 2, s = f & 3;
        const int n  = t * 16 + (l & 15);
        const int k0 = s * 32 + (l >> 4) * 8;
        const f32x4* p = reinterpret_cast<const f32x4*>(W + n * 128 + k0);
        wlds[e] = pack8(p[0], p[1]);
    }
    // bias for this lane's 4 consecutive out-cols per t-tile:
    // acc[t][r] = out[.][t*16 + kg*4 + r]
    f32x4 bv4[8];
#pragma unroll
    for (int t = 0; t < 8; ++t)
        bv4[t] = *reinterpret_cast<const f32x4*>(bias + t * 16 + (kg << 2));
    __syncthreads();

    const f32x4 zero4 = {0.f, 0.f, 0.f, 0.f};

    for (int tile = wid; tile < n_tiles; tile += n_waves) {
        const int r0   = tile << 4;
        const int arow = r0 + ln;                 // this lane's x/out row
        const bool m   = amask[arow] != 0;        // 4-byte word test

        // ---- x fragments: exec-predicated direct-from-global loads ----
        const float* xr = x + (size_t)arow * 128 + kg * 8;
        short8 a[4];
#pragma unroll
        for (int s = 0; s < 4; ++s) {
            f32x4 lo = zero4, hi = zero4;
            if (m) {
                const f32x4* p = reinterpret_cast<const f32x4*>(xr + s * 32);
                lo = p[0]; hi = p[1];
            }
            a[s] = pack8(lo, hi);
        }

        // ---- acc init: bias (zeroed for masked-out rows; a==0 keeps it 0)
        f32x4 acc[8];
#pragma unroll
        for (int t = 0; t < 8; ++t)
            acc[t] = m ? bv4[t] : zero4;

        // ---- MFMA, swapped: D = Wtile * x^T -> lane holds out[arow][4 cols]
#pragma unroll
        for (int s = 0; s < 4; ++s)
#pragma unroll
            for (int t = 0; t < 8; ++t)
                acc[t] = __builtin_amdgcn_mfma_f32_16x16x32_bf16(
                             wlds[(t * 4 + s) * 64 + lane], a[s], acc[t], 0, 0, 0);

        // ---- store via per-wave LDS transpose: full-line contiguous stores
        // pass h covers out cols [h*64, h*64+64) (bytes [h*256,+256) per row)
#pragma unroll
        for (int h = 0; h < 2; ++h) {
            // write: lane (ln,kg), t' = t-4h: tile pos row=ln, col'=t'*16+kg*4
#pragma unroll
            for (int tt = 0; tt < 4; ++tt)
                *reinterpret_cast<f32x4*>(&obnc[wib][ln][tt * 16 + (kg << 2)])
                    = acc[4 * h + tt];
            // read linear + store: instr i covers rows 4i..4i+3, 256B each
            // (each 128B line fully covered within this one instruction)
#pragma unroll
            for (int i = 0; i < 4; ++i) {
                const f32x4 v = *reinterpret_cast<const f32x4*>(
                    &obnc[wib][4 * i + kg][ln << 2]);
                *reinterpret_cast<f32x4*>(
                    out + (size_t)(r0 + 4 * i + kg) * 128 + h * 64 + (ln << 2)) = v;
            }
        }
    }
}

extern "C" void kernel_launch(void* const* d_in, const int* in_sizes, int n_in,
                              void* d_out, int out_size, void* d_ws, size_t ws_size,
                              hipStream_t stream) {
    const float* x     = (const float*)d_in[0];
    const int*   amask = (const int*)d_in[1];
    const float* W     = (const float*)d_in[2];
    const float* b     = (const float*)d_in[3];
    float*       out   = (float*)d_out;

    const int n_rows  = in_sizes[1];      // 1,000,000 (multiple of 16)
    const int n_tiles = n_rows >> 4;      // 62,500
    // LDS 49K/block -> 3 blocks/CU resident: 256 CU * 3 = 768 blocks.
    const int blocks  = 768;
    const int n_waves = blocks * 4;

    hipLaunchKernelGGL(masked_linear_kernel, dim3(blocks), dim3(256), 0, stream,
                       x, amask, W, b, out, n_tiles, n_waves);
}